// Round 5
// baseline (665.708 us; speedup 1.0000x reference)
//
#include <hip/hip_runtime.h>
#include <hip/hip_bf16.h>
#include <stdint.h>

#define N_NODES 50000
#define N_EDGES 800000

typedef __attribute__((ext_vector_type(8))) __bf16 bf16x8;
typedef __attribute__((ext_vector_type(4))) float floatx4;

// ---------------------------------------------------------------- bf16 split helpers
__device__ __forceinline__ unsigned short f2bf(float f) {
    union { float f; unsigned u; } v; v.f = f;
    unsigned r = v.u + 0x7fffu + ((v.u >> 16) & 1u);   // RNE
    return (unsigned short)(r >> 16);
}
__device__ __forceinline__ float bf2f(unsigned short h) {
    union { unsigned u; float f; } v; v.u = ((unsigned)h) << 16;
    return v.f;
}

// ---------------------------------------------------------------- degree count
__global__ __launch_bounds__(256) void count_deg_kernel(
    const int* __restrict__ dst, unsigned* __restrict__ cnt, int nE)
{
    int i = blockIdx.x * blockDim.x + threadIdx.x;
    if (i < nE) {
        unsigned d = (unsigned)dst[i];
        if (d < N_NODES) atomicAdd(&cnt[d], 1u);
    }
}

// ---------------------------------------------------------------- hierarchical scan
__global__ __launch_bounds__(256) void block_reduce_kernel(
    const unsigned* __restrict__ cnt, unsigned* __restrict__ blockSums, int n)
{
    __shared__ unsigned s[256];
    int b = blockIdx.x;
    int base = b * 1024;
    unsigned v = 0;
    for (int i = threadIdx.x; i < 1024; i += 256) {
        int idx = base + i;
        v += (idx < n) ? cnt[idx] : 0u;
    }
    s[threadIdx.x] = v; __syncthreads();
    for (int st = 128; st > 0; st >>= 1) {
        if (threadIdx.x < st) s[threadIdx.x] += s[threadIdx.x + st];
        __syncthreads();
    }
    if (threadIdx.x == 0) blockSums[b] = s[0];
}

__global__ __launch_bounds__(64) void scan_sums_kernel(
    unsigned* __restrict__ blockSums, unsigned* __restrict__ off, int nb, int n)
{
    __shared__ unsigned s[64];
    int t = threadIdx.x;
    unsigned v = (t < nb) ? blockSums[t] : 0u;
    s[t] = v; __syncthreads();
    for (int st = 1; st < 64; st <<= 1) {
        unsigned add = (t >= st) ? s[t - st] : 0u;
        __syncthreads();
        s[t] += add;
        __syncthreads();
    }
    if (t < nb) blockSums[t] = s[t] - v;   // exclusive
    if (t == 0) off[n] = s[63];            // grand total
}

// also emits dinv = rsqrt(deg+1)
__global__ __launch_bounds__(1024) void block_scan_kernel(
    const unsigned* __restrict__ cnt, const unsigned* __restrict__ blockSums,
    unsigned* __restrict__ off, float* __restrict__ dinv, int n)
{
    __shared__ unsigned s[1024];
    int b = blockIdx.x, t = threadIdx.x;
    int i = b * 1024 + t;
    unsigned v = (i < n) ? cnt[i] : 0u;
    s[t] = v; __syncthreads();
    for (int st = 1; st < 1024; st <<= 1) {
        unsigned add = (t >= st) ? s[t - st] : 0u;
        __syncthreads();
        s[t] += add;
        __syncthreads();
    }
    if (i < n) {
        off[i]  = blockSums[b] + s[t] - v;
        dinv[i] = rsqrtf((float)(v + 1u));
    }
}

// ---------------------------------------------------------------- CSR fill
__global__ __launch_bounds__(256) void fill_csr_kernel(
    const int* __restrict__ src, const int* __restrict__ dst,
    const unsigned* __restrict__ off, unsigned* __restrict__ cursor,
    int* __restrict__ csr_src, int nE)
{
    int i = blockIdx.x * blockDim.x + threadIdx.x;
    if (i < nE) {
        unsigned d = (unsigned)dst[i];
        unsigned s = (unsigned)src[i];
        if (d < N_NODES && s < N_NODES) {
            unsigned slot = off[d] + atomicAdd(&cursor[d], 1u);
            csr_src[slot] = (int)s;
        }
    }
}

// ---------------------------------------------------------------- W pre-split + transpose
// W: K x N row-major fp32  ->  WTh/WTl: N x K bf16 (hi/lo), k-contiguous
__global__ __launch_bounds__(256) void split_w_kernel(
    const float* __restrict__ W, unsigned short* __restrict__ Th,
    unsigned short* __restrict__ Tl, int K, int N)
{
    int i = blockIdx.x * blockDim.x + threadIdx.x;
    if (i < K * N) {
        int k = i / N;
        int n = i - k * N;
        float w = W[i];
        unsigned short hi = f2bf(w);
        unsigned short lo = f2bf(w - bf2f(hi));
        Th[(size_t)n * K + k] = hi;
        Tl[(size_t)n * K + k] = lo;
    }
}

// ---------------------------------------------------------------- X pre-split
// x[:,588:1100] (stride 1100) -> Xh/Xl: 50000 x 512 bf16
__global__ __launch_bounds__(256) void split_x_kernel(
    const float* __restrict__ x, unsigned short* __restrict__ Xh,
    unsigned short* __restrict__ Xl)
{
    int i = blockIdx.x * 256 + threadIdx.x;        // over 50000*128 float4 groups
    int row  = i >> 7;
    int col4 = (i & 127) << 2;
    if (row < N_NODES) {
        float4 v = *(const float4*)(x + (size_t)row * 1100 + 588 + col4);
        union { unsigned short us[4]; ushort4 v4; } ph, pl;
        float f[4] = {v.x, v.y, v.z, v.w};
        #pragma unroll
        for (int e = 0; e < 4; ++e) {
            unsigned short hi = f2bf(f[e]);
            ph.us[e] = hi;
            pl.us[e] = f2bf(f[e] - bf2f(hi));
        }
        *(ushort4*)(Xh + (size_t)row * 512 + col4) = ph.v4;
        *(ushort4*)(Xl + (size_t)row * 512 + col4) = pl.v4;
    }
}

// ---------------------------------------------------------------- MFMA split-bf16 GEMM
// Y[m,n] = dinv[m] * sum_k A[m,k] * W[k,n]
// A: pre-split bf16 pair (Ah/Al, pitch apitch). B: pre-split transposed bf16 BT[n*K+k].
// Tile 128x128, BK=32, 4 waves 2x2, each wave 64x64 via 4x4 16x16x32 MFMAs.
// 3 passes: hi*hi + lo*hi + hi*lo (fp32-equivalent accuracy).
#define GBM 128
#define GBN 128
#define GBK 32

// swizzled LDS chunk offset (elements). Row stride 32 ushorts = 64B; the
// quad-chunk xor breaks the 8-bank aliasing of the 64B stride.
__device__ __forceinline__ int chunk_off(int row, int q) {
    return row * 32 + ((q ^ ((row >> 1) & 3)) << 3);
}

__global__ __launch_bounds__(256) void gemm_mfma_kernel(
    const unsigned short* __restrict__ Ah, const unsigned short* __restrict__ Al, int apitch,
    const unsigned short* __restrict__ BTh, const unsigned short* __restrict__ BTl,
    const float* __restrict__ dinv, float* __restrict__ Y,
    int M, int K, int N)
{
    __shared__ unsigned short sAh[GBM * GBK];
    __shared__ unsigned short sAl[GBM * GBK];
    __shared__ unsigned short sBh[GBN * GBK];
    __shared__ unsigned short sBl[GBN * GBK];

    const int t    = threadIdx.x;
    const int bm   = blockIdx.x * GBM;
    const int bn   = blockIdx.y * GBN;
    const int w    = t >> 6;
    const int lane = t & 63;
    const int wx   = w & 1;
    const int wy   = w >> 1;
    const int ml   = lane & 15;
    const int quad = lane >> 4;

    // staging role: 2 threads per tile row, each covers 16 k (2 chunks of 8)
    const int sr = t >> 1;
    const int q0 = (t & 1) * 2;

    floatx4 zero4 = {0.f, 0.f, 0.f, 0.f};
    floatx4 acc[4][4];
    #pragma unroll
    for (int i = 0; i < 4; ++i)
        #pragma unroll
        for (int j = 0; j < 4; ++j) acc[i][j] = zero4;

    for (int k0 = 0; k0 < K; k0 += GBK) {
        // ---- stage A (bf16 pair)
        {
            int gr = bm + sr;
            #pragma unroll
            for (int c = 0; c < 2; ++c) {
                int q = q0 + c;
                uint4 vh, vl;
                if (gr < M) {
                    vh = *(const uint4*)(Ah + (size_t)gr * apitch + k0 + q * 8);
                    vl = *(const uint4*)(Al + (size_t)gr * apitch + k0 + q * 8);
                } else {
                    vh = make_uint4(0,0,0,0);
                    vl = make_uint4(0,0,0,0);
                }
                int off = chunk_off(sr, q);
                *(uint4*)&sAh[off] = vh;
                *(uint4*)&sAl[off] = vl;
            }
        }
        // ---- stage B (bf16 pair, n-major pitch K)
        {
            const unsigned short* bh = BTh + (size_t)(bn + sr) * K + k0;
            const unsigned short* bl = BTl + (size_t)(bn + sr) * K + k0;
            #pragma unroll
            for (int c = 0; c < 2; ++c) {
                int q = q0 + c;
                uint4 vh = *(const uint4*)(bh + q * 8);
                uint4 vl = *(const uint4*)(bl + q * 8);
                int off = chunk_off(sr, q);
                *(uint4*)&sBh[off] = vh;
                *(uint4*)&sBl[off] = vl;
            }
        }
        __syncthreads();

        // ---- fragments
        bf16x8 fAh[4], fAl[4], fBh[4], fBl[4];
        #pragma unroll
        for (int i = 0; i < 4; ++i) {
            int row = wy * 64 + i * 16 + ml;
            int off = chunk_off(row, quad);
            fAh[i] = *(const bf16x8*)&sAh[off];
            fAl[i] = *(const bf16x8*)&sAl[off];
        }
        #pragma unroll
        for (int j = 0; j < 4; ++j) {
            int nrow = wx * 64 + j * 16 + ml;
            int off = chunk_off(nrow, quad);
            fBh[j] = *(const bf16x8*)&sBh[off];
            fBl[j] = *(const bf16x8*)&sBl[off];
        }

        // ---- 3-pass MFMA
        #pragma unroll
        for (int i = 0; i < 4; ++i)
            #pragma unroll
            for (int j = 0; j < 4; ++j) {
                floatx4 c = acc[i][j];
                c = __builtin_amdgcn_mfma_f32_16x16x32_bf16(fAh[i], fBh[j], c, 0, 0, 0);
                c = __builtin_amdgcn_mfma_f32_16x16x32_bf16(fAl[i], fBh[j], c, 0, 0, 0);
                c = __builtin_amdgcn_mfma_f32_16x16x32_bf16(fAh[i], fBl[j], c, 0, 0, 0);
                acc[i][j] = c;
            }
        __syncthreads();
    }

    // ---- epilogue: row = quad*4 + reg, col = ml
    #pragma unroll
    for (int i = 0; i < 4; ++i) {
        int rb = bm + wy * 64 + i * 16 + quad * 4;
        float sc[4];
        #pragma unroll
        for (int r = 0; r < 4; ++r) sc[r] = (rb + r < M) ? dinv[rb + r] : 0.f;
        #pragma unroll
        for (int j = 0; j < 4; ++j) {
            int col = bn + wx * 64 + j * 16 + ml;
            #pragma unroll
            for (int r = 0; r < 4; ++r) {
                int grow = rb + r;
                if (grow < M) Y[(size_t)grow * N + col] = acc[i][j][r] * sc[r];
            }
        }
    }
}

// ---------------------------------------------------------------- aggregation, F=256 -> bf16 hi/lo h
// 4 nodes per 256-block, 64 lanes per node, float4 per lane, 8 rows in flight.
__global__ __launch_bounds__(256) void aggregate256_kernel(
    const float* __restrict__ Y, const int* __restrict__ csr_src,
    const unsigned* __restrict__ off, const float* __restrict__ dinv,
    const float* __restrict__ bias,
    unsigned short* __restrict__ Hh, unsigned short* __restrict__ Hl)
{
    const int v  = blockIdx.x * 4 + (threadIdx.x >> 6);
    const int f0 = (threadIdx.x & 63) * 4;

    float4 a0 = *(const float4*)(Y + (size_t)v * 256 + f0);   // self loop
    float4 a1 = make_float4(0.f,0.f,0.f,0.f);
    float4 a2 = make_float4(0.f,0.f,0.f,0.f);
    float4 a3 = make_float4(0.f,0.f,0.f,0.f);

    const unsigned e0 = off[v], e1 = off[v + 1];
    unsigned j = e0;
    for (; j + 8 <= e1; j += 8) {
        int u[8];
        #pragma unroll
        for (int q = 0; q < 8; ++q) u[q] = csr_src[j + q];
        float4 m[8];
        #pragma unroll
        for (int q = 0; q < 8; ++q) m[q] = *(const float4*)(Y + (size_t)u[q] * 256 + f0);
        #pragma unroll
        for (int q = 0; q < 8; q += 4) {
            a0.x += m[q+0].x; a0.y += m[q+0].y; a0.z += m[q+0].z; a0.w += m[q+0].w;
            a1.x += m[q+1].x; a1.y += m[q+1].y; a1.z += m[q+1].z; a1.w += m[q+1].w;
            a2.x += m[q+2].x; a2.y += m[q+2].y; a2.z += m[q+2].z; a2.w += m[q+2].w;
            a3.x += m[q+3].x; a3.y += m[q+3].y; a3.z += m[q+3].z; a3.w += m[q+3].w;
        }
    }
    for (; j < e1; ++j) {
        float4 m = *(const float4*)(Y + (size_t)csr_src[j] * 256 + f0);
        a0.x += m.x; a0.y += m.y; a0.z += m.z; a0.w += m.w;
    }
    float sx = (a0.x + a1.x) + (a2.x + a3.x);
    float sy = (a0.y + a1.y) + (a2.y + a3.y);
    float sz = (a0.z + a1.z) + (a2.z + a3.z);
    float sw = (a0.w + a1.w) + (a2.w + a3.w);

    float dv = dinv[v];
    float4 b = *(const float4*)(bias + f0);
    float r[4];
    r[0] = fmaxf(sx * dv + b.x, 0.f);
    r[1] = fmaxf(sy * dv + b.y, 0.f);
    r[2] = fmaxf(sz * dv + b.z, 0.f);
    r[3] = fmaxf(sw * dv + b.w, 0.f);

    union { unsigned short us[4]; ushort4 v4; } ph, pl;
    #pragma unroll
    for (int e = 0; e < 4; ++e) {
        unsigned short hi = f2bf(r[e]);
        ph.us[e] = hi;
        pl.us[e] = f2bf(r[e] - bf2f(hi));
    }
    *(ushort4*)(Hh + (size_t)v * 256 + f0) = ph.v4;
    *(ushort4*)(Hl + (size_t)v * 256 + f0) = pl.v4;
}

// ---------------------------------------------------------------- aggregation, F=128 -> fp32 out
// 4 nodes per 256-block, 64 lanes per node, float2 per lane, 8 rows in flight.
__global__ __launch_bounds__(256) void aggregate128_kernel(
    const float* __restrict__ Y, const int* __restrict__ csr_src,
    const unsigned* __restrict__ off, const float* __restrict__ dinv,
    const float* __restrict__ bias, float* __restrict__ out)
{
    const int v  = blockIdx.x * 4 + (threadIdx.x >> 6);
    const int f0 = (threadIdx.x & 63) * 2;

    float2 a0 = *(const float2*)(Y + (size_t)v * 128 + f0);   // self loop
    float2 a1 = make_float2(0.f,0.f);
    float2 a2 = make_float2(0.f,0.f);
    float2 a3 = make_float2(0.f,0.f);

    const unsigned e0 = off[v], e1 = off[v + 1];
    unsigned j = e0;
    for (; j + 8 <= e1; j += 8) {
        int u[8];
        #pragma unroll
        for (int q = 0; q < 8; ++q) u[q] = csr_src[j + q];
        float2 m[8];
        #pragma unroll
        for (int q = 0; q < 8; ++q) m[q] = *(const float2*)(Y + (size_t)u[q] * 128 + f0);
        #pragma unroll
        for (int q = 0; q < 8; q += 4) {
            a0.x += m[q+0].x; a0.y += m[q+0].y;
            a1.x += m[q+1].x; a1.y += m[q+1].y;
            a2.x += m[q+2].x; a2.y += m[q+2].y;
            a3.x += m[q+3].x; a3.y += m[q+3].y;
        }
    }
    for (; j < e1; ++j) {
        float2 m = *(const float2*)(Y + (size_t)csr_src[j] * 128 + f0);
        a0.x += m.x; a0.y += m.y;
    }
    float sx = (a0.x + a1.x) + (a2.x + a3.x);
    float sy = (a0.y + a1.y) + (a2.y + a3.y);

    float dv = dinv[v];
    float2 b = *(const float2*)(bias + f0);
    float2 r = make_float2(sx * dv + b.x, sy * dv + b.y);
    *(float2*)(out + (size_t)v * 128 + f0) = r;
}

// ---------------------------------------------------------------- launch
extern "C" void kernel_launch(void* const* d_in, const int* in_sizes, int n_in,
                              void* d_out, int out_size, void* d_ws, size_t ws_size,
                              hipStream_t stream)
{
    const float* x  = (const float*)d_in[0];      // 50000 x 1100
    const int*   ei = (const int*)d_in[1];        // 2 x 800000 (int32)
    const float* W1 = (const float*)d_in[2];      // 512 x 256
    const float* b1 = (const float*)d_in[3];      // 256
    const float* W2 = (const float*)d_in[4];      // 256 x 128
    const float* b2 = (const float*)d_in[5];      // 128
    float*       out = (float*)d_out;             // 50000 x 128

    const int* e_src = ei;
    const int* e_dst = ei + N_EDGES;

    char* ws = (char*)d_ws;
    size_t o = 0;
    auto carve = [&](size_t bytes) -> char* {
        char* p = ws + o;
        o = (o + bytes + 511) & ~(size_t)511;
        return p;
    };
    unsigned*       cnt    = (unsigned*)carve((size_t)N_NODES * 4);
    unsigned*       cursor = (unsigned*)carve((size_t)N_NODES * 4);
    unsigned*       off    = (unsigned*)carve((size_t)(N_NODES + 1) * 4);
    unsigned*       bsums  = (unsigned*)carve(64 * 4);
    float*          dinv   = (float*)carve((size_t)N_NODES * 4);
    int*            csr    = (int*)carve((size_t)N_EDGES * 4);
    unsigned short* WT1h   = (unsigned short*)carve((size_t)512 * 256 * 2);
    unsigned short* WT1l   = (unsigned short*)carve((size_t)512 * 256 * 2);
    unsigned short* WT2h   = (unsigned short*)carve((size_t)256 * 128 * 2);
    unsigned short* WT2l   = (unsigned short*)carve((size_t)256 * 128 * 2);
    unsigned short* Xh     = (unsigned short*)carve((size_t)N_NODES * 512 * 2);
    unsigned short* Xl     = (unsigned short*)carve((size_t)N_NODES * 512 * 2);
    float*          y      = (float*)carve((size_t)N_NODES * 256 * 4);   // y1, reused as y2
    unsigned short* Hh     = (unsigned short*)carve((size_t)N_NODES * 256 * 2);
    unsigned short* Hl     = (unsigned short*)carve((size_t)N_NODES * 256 * 2);
    (void)ws_size;

    // cnt and cursor are adjacent in the carve — one memset covers both
    size_t cntAligned = ((size_t)N_NODES * 4 + 511) & ~(size_t)511;
    hipMemsetAsync(cnt, 0, cntAligned + (size_t)N_NODES * 4, stream);

    const int nScanBlocks = (N_NODES + 1023) / 1024;   // 49

    count_deg_kernel<<<(N_EDGES + 255) / 256, 256, 0, stream>>>(e_dst, cnt, N_EDGES);
    block_reduce_kernel<<<nScanBlocks, 256, 0, stream>>>(cnt, bsums, N_NODES);
    scan_sums_kernel<<<1, 64, 0, stream>>>(bsums, off, nScanBlocks, N_NODES);
    block_scan_kernel<<<nScanBlocks, 1024, 0, stream>>>(cnt, bsums, off, dinv, N_NODES);
    fill_csr_kernel<<<(N_EDGES + 255) / 256, 256, 0, stream>>>(e_src, e_dst, off, cursor, csr, N_EDGES);

    split_w_kernel<<<(512 * 256 + 255) / 256, 256, 0, stream>>>(W1, WT1h, WT1l, 512, 256);
    split_w_kernel<<<(256 * 128 + 255) / 256, 256, 0, stream>>>(W2, WT2h, WT2l, 256, 128);
    split_x_kernel<<<(N_NODES * 128 + 255) / 256, 256, 0, stream>>>(x, Xh, Xl);

    // layer 1: y = dinv * (X @ W1)
    {
        dim3 grid((N_NODES + GBM - 1) / GBM, 256 / GBN);
        gemm_mfma_kernel<<<grid, 256, 0, stream>>>(
            Xh, Xl, 512, WT1h, WT1l, dinv, y, N_NODES, 512, 256);
    }
    // h = relu(dinv * rowsum(y) + b1)  -> bf16 hi/lo
    aggregate256_kernel<<<N_NODES / 4, 256, 0, stream>>>(y, csr, off, dinv, b1, Hh, Hl);

    // layer 2: y = dinv * (h @ W2)
    {
        dim3 grid((N_NODES + GBM - 1) / GBM, 128 / GBN);
        gemm_mfma_kernel<<<grid, 256, 0, stream>>>(
            Hh, Hl, 256, WT2h, WT2l, dinv, y, N_NODES, 256, 128);
    }
    // out = dinv * rowsum(y) + b2
    aggregate128_kernel<<<N_NODES / 4, 256, 0, stream>>>(y, csr, off, dinv, b2, out);
}